// Round 14
// baseline (1722.775 us; speedup 1.0000x reference)
//
#include <hip/hip_runtime.h>
#include <hip/hip_bf16.h>
#include <math.h>

typedef float f4 __attribute__((ext_vector_type(4)));
typedef __attribute__((ext_vector_type(8))) short short8;

#define NTAGS 600
#define CEw   48
#define HH    256
#define TSEQ  96
#define CLW   16
#define LMAXD 24
#define NROWS 6144
#define DIN   192
#define VCD   200

__device__ __forceinline__ float sigf(float x){ return 1.0f/(1.0f+expf(-x)); }
__device__ __forceinline__ ushort bhi_u(float v){ __hip_bfloat16 h = __float2bfloat16(v); return *(ushort*)&h; }
__device__ __forceinline__ float ub_f(ushort u){ __hip_bfloat16 h = *(__hip_bfloat16*)&u; return __bfloat162float(h); }

// ============ generalized MFMA 3-term GEMM (per-segment LDS staging; proven) ============
template<int ACT, int HS, int KK>
__global__ __launch_bounds__(256)
void gemm3_k(const ushort* __restrict__ Ahi, const ushort* __restrict__ Alo,
             const ushort* __restrict__ Bhi, const ushort* __restrict__ Blo,
             const float* __restrict__ bias, float* __restrict__ C,
             ushort* __restrict__ Hhi, ushort* __restrict__ Hlo,
             int Nc, int ldC)
{
    __shared__ __align__(16) ushort As[128 * 64];
    __shared__ __align__(16) ushort Bs[128 * 64];
    const int tid = threadIdx.x;
    const int m0 = blockIdx.x * 128;
    const int n0 = blockIdx.y * 128;
    const int w = tid >> 6, l = tid & 63;
    const int wr = (w >> 1) * 64, wc = (w & 1) * 64;
    f4 acc[4][4];
    #pragma unroll
    for (int i = 0; i < 4; ++i)
        #pragma unroll
        for (int j = 0; j < 4; ++j) acc[i][j] = (f4){0.f,0.f,0.f,0.f};

    #pragma unroll
    for (int seg = 0; seg < 3; ++seg) {
        const ushort* Ap = (seg == 1) ? Alo : Ahi;
        const ushort* Bp = (seg == 2) ? Blo : Bhi;
        #pragma unroll
        for (int kt = 0; kt < KK; kt += 64) {
            #pragma unroll
            for (int i = 0; i < 4; ++i) {
                int c = w * 4 + i;
                int row = c * 8 + (l >> 3);
                int col16 = l & 7;
                __builtin_amdgcn_global_load_lds(
                    (const __attribute__((address_space(1))) void*)(Ap + (size_t)(m0 + row) * KK + kt + col16 * 8),
                    (__attribute__((address_space(3))) void*)((char*)As + c * 1024 + l * 16), 16, 0, 0);
                __builtin_amdgcn_global_load_lds(
                    (const __attribute__((address_space(1))) void*)(Bp + (size_t)(n0 + row) * KK + kt + col16 * 8),
                    (__attribute__((address_space(3))) void*)((char*)Bs + c * 1024 + l * 16), 16, 0, 0);
            }
            __syncthreads();
            #pragma unroll
            for (int kk = 0; kk < 64; kk += 32) {
                short8 a[4], b[4];
                #pragma unroll
                for (int mf = 0; mf < 4; ++mf)
                    a[mf] = *(const short8*)(As + (wr + mf * 16 + (l & 15)) * 64 + kk + (l >> 4) * 8);
                #pragma unroll
                for (int nf = 0; nf < 4; ++nf)
                    b[nf] = *(const short8*)(Bs + (wc + nf * 16 + (l & 15)) * 64 + kk + (l >> 4) * 8);
                #pragma unroll
                for (int mf = 0; mf < 4; ++mf)
                    #pragma unroll
                    for (int nf = 0; nf < 4; ++nf)
                        acc[mf][nf] = __builtin_amdgcn_mfma_f32_16x16x32_bf16(a[mf], b[nf], acc[mf][nf], 0, 0, 0);
            }
            __syncthreads();
        }
    }
    #pragma unroll
    for (int nf = 0; nf < 4; ++nf) {
        int n = n0 + wc + nf * 16 + (l & 15);
        if (n >= Nc) continue;
        float bv = bias[n];
        #pragma unroll
        for (int mf = 0; mf < 4; ++mf) {
            int mrow = m0 + wr + mf * 16 + (l >> 4) * 4;
            #pragma unroll
            for (int q2 = 0; q2 < 4; ++q2) {
                float v = acc[mf][nf][q2] + bv;
                if (ACT == 1) v = tanhf(v);
                size_t o = (size_t)(mrow + q2) * ldC + n;
                C[o] = v;
                if (HS) {
                    ushort hi = bhi_u(v);
                    Hhi[o] = hi;
                    Hlo[o] = bhi_u(v - ub_f(hi));
                }
            }
        }
    }
}

// ============ FUSED decode step: prologue(argmax+GRU for own 32 rows) -> GEMM ============
// grid (192, nY), 256 thr. m-tile 32 rows, n-tile 128 cols (n0base + y*128).
// LDS: hHi[32][256] swz (16KB) + hLo (16KB) persistent; Bs[128][64] (16KB) per-plane staged.
__global__ __launch_bounds__(256)
void dec_k(float* __restrict__ ghW, const float* __restrict__ ghR,
           const ushort* __restrict__ hRhi, const ushort* __restrict__ hRlo,
           ushort* __restrict__ hWhi, ushort* __restrict__ hWlo,
           const float* __restrict__ git,
           const ushort* __restrict__ Bhi, const ushort* __restrict__ Blo,
           const float* __restrict__ bias, float* __restrict__ out_lem,
           int t, int n0base)
{
    __shared__ __align__(16) char smem[49152];
    ushort* Bsm = (ushort*)(smem + 32768);
    __shared__ int sprev[32];
    const int tid = threadIdx.x;
    const int m0 = blockIdx.x * 32;
    const int n0 = n0base + blockIdx.y * 128;

    // ---- prologue: previous-step argmax ----
    if (t >= 2) {
        int r = tid >> 3, c = tid & 7;
        const float* L = out_lem + ((size_t)(m0 + r) * LMAXD + (t - 2)) * VCD;
        float best = -3.4e38f; int bi = 0;
        for (int i = c; i < VCD; i += 8) {
            float v = L[i];
            if (v > best) { best = v; bi = i; }
        }
        #pragma unroll
        for (int d = 1; d < 8; d <<= 1) {
            float ov = __shfl_xor(best, d);
            int   oi = __shfl_xor(bi, d);
            if (ov > best || (ov == best && oi < bi)) { best = ov; bi = oi; }
        }
        if (c == 0) sprev[r] = bi;
        __syncthreads();
    } else if (t == 1) {
        if (tid < 32) sprev[tid] = 3;   // BOS
        __syncthreads();
    }

    // ---- prologue: GRU update (or copy at t==0) into swizzled LDS + global planes ----
    if (t == 0) {
        #pragma unroll 4
        for (int i = 0; i < 32; ++i) {
            size_t o = (size_t)(m0 + i) * 256 + tid;
            int so = i * 512 + ((2 * tid) ^ ((i & 7) << 4));
            *(ushort*)(smem + so) = hRhi[o];
            *(ushort*)(smem + 16384 + so) = hRlo[o];
        }
    } else {
        #pragma unroll 2
        for (int i = 0; i < 32; ++i) {
            int row = m0 + i;
            const float* g  = ghR + (size_t)row * 768;
            const float* gi = git + (size_t)sprev[i] * 768;
            int j = tid;
            float rg = sigf(gi[j] + g[j]);
            float z  = sigf(gi[256 + j] + g[256 + j]);
            float nn = tanhf(gi[512 + j] + rg * g[512 + j]);
            size_t o = (size_t)row * 256 + j;
            float hold = ub_f(hRhi[o]) + ub_f(hRlo[o]);
            float hv = (1.0f - z) * nn + z * hold;
            ushort hi = bhi_u(hv);
            ushort lo = bhi_u(hv - ub_f(hi));
            hWhi[o] = hi;
            hWlo[o] = lo;
            int so = i * 512 + ((2 * j) ^ ((i & 7) << 4));
            *(ushort*)(smem + so) = hi;
            *(ushort*)(smem + 16384 + so) = lo;
        }
    }
    __syncthreads();

    // ---- GEMM: [gh_t | logits_{t-1}] tile = h_t(32 rows) @ B(128 cols)^T ----
    const int w = tid >> 6, l = tid & 63;
    const int wc = w * 32;
    const int lr = l & 15;
    const int lk = (l >> 4) * 8;
    f4 acc[2][2];
    #pragma unroll
    for (int i = 0; i < 2; ++i)
        #pragma unroll
        for (int j = 0; j < 2; ++j) acc[i][j] = (f4){0.f,0.f,0.f,0.f};

    #pragma unroll
    for (int kt = 0; kt < 256; kt += 64) {
        // A frags for this kt (hi kept for both B phases)
        short8 ah[2][2], al[2][2];
        #pragma unroll
        for (int mf = 0; mf < 2; ++mf)
            #pragma unroll
            for (int kx = 0; kx < 2; ++kx) {
                int row = mf * 16 + lr;
                int j0 = kt + kx * 32 + lk;
                int so = row * 512 + ((2 * j0) ^ ((row & 7) << 4));
                ah[mf][kx] = *(const short8*)(smem + so);
                al[mf][kx] = *(const short8*)(smem + 16384 + so);
            }
        // phase 1: B-hi
        #pragma unroll
        for (int i = 0; i < 4; ++i) {
            int c = w * 4 + i;
            int brow = c * 8 + (l >> 3);
            __builtin_amdgcn_global_load_lds(
                (const __attribute__((address_space(1))) void*)(Bhi + (size_t)(n0 + brow) * 256 + kt + (l & 7) * 8),
                (__attribute__((address_space(3))) void*)(smem + 32768 + c * 1024 + l * 16), 16, 0, 0);
        }
        __syncthreads();
        #pragma unroll
        for (int kx = 0; kx < 2; ++kx) {
            short8 bh[2];
            #pragma unroll
            for (int nf = 0; nf < 2; ++nf)
                bh[nf] = *(const short8*)(Bsm + (wc + nf * 16 + lr) * 64 + kx * 32 + lk);
            #pragma unroll
            for (int mf = 0; mf < 2; ++mf)
                #pragma unroll
                for (int nf = 0; nf < 2; ++nf) {
                    acc[mf][nf] = __builtin_amdgcn_mfma_f32_16x16x32_bf16(ah[mf][kx], bh[nf], acc[mf][nf], 0, 0, 0);
                    acc[mf][nf] = __builtin_amdgcn_mfma_f32_16x16x32_bf16(al[mf][kx], bh[nf], acc[mf][nf], 0, 0, 0);
                }
        }
        __syncthreads();
        // phase 2: B-lo
        #pragma unroll
        for (int i = 0; i < 4; ++i) {
            int c = w * 4 + i;
            int brow = c * 8 + (l >> 3);
            __builtin_amdgcn_global_load_lds(
                (const __attribute__((address_space(1))) void*)(Blo + (size_t)(n0 + brow) * 256 + kt + (l & 7) * 8),
                (__attribute__((address_space(3))) void*)(smem + 32768 + c * 1024 + l * 16), 16, 0, 0);
        }
        __syncthreads();
        #pragma unroll
        for (int kx = 0; kx < 2; ++kx) {
            short8 bl[2];
            #pragma unroll
            for (int nf = 0; nf < 2; ++nf)
                bl[nf] = *(const short8*)(Bsm + (wc + nf * 16 + lr) * 64 + kx * 32 + lk);
            #pragma unroll
            for (int mf = 0; mf < 2; ++mf)
                #pragma unroll
                for (int nf = 0; nf < 2; ++nf)
                    acc[mf][nf] = __builtin_amdgcn_mfma_f32_16x16x32_bf16(ah[mf][kx], bl[nf], acc[mf][nf], 0, 0, 0);
        }
        __syncthreads();
    }
    #pragma unroll
    for (int nf = 0; nf < 2; ++nf) {
        int col = n0 + wc + nf * 16 + lr;
        float bv = bias[col];
        #pragma unroll
        for (int mf = 0; mf < 2; ++mf) {
            int mrow = m0 + mf * 16 + (l >> 4) * 4;
            #pragma unroll
            for (int q2 = 0; q2 < 4; ++q2) {
                float v = acc[mf][nf][q2] + bv;
                int m = mrow + q2;
                if (col < 768) {
                    ghW[(size_t)m * 768 + col] = v;
                } else {
                    int c2 = col - 768;
                    if (c2 < VCD && t > 0)
                        out_lem[((size_t)m * LMAXD + (t - 1)) * VCD + c2] = v;
                }
            }
        }
    }
}

// ============ fallback decode GEMM (R13, proven) ============
__global__ __launch_bounds__(256)
void gemmC_k(const ushort* __restrict__ Ahi, const ushort* __restrict__ Alo,
             const ushort* __restrict__ Bhi, const ushort* __restrict__ Blo,
             const float* __restrict__ bias,
             float* __restrict__ gh, float* __restrict__ lem, int ncol_gh)
{
    __shared__ __align__(16) ushort AsH[64 * 64];
    __shared__ __align__(16) ushort AsL[64 * 64];
    __shared__ __align__(16) ushort BsH[128 * 64];
    __shared__ __align__(16) ushort BsL[128 * 64];
    const int tid = threadIdx.x;
    const int m0 = blockIdx.x * 64;
    const int n0 = blockIdx.y * 128;
    const int w = tid >> 6, l = tid & 63;
    const int wr = (w >> 1) * 32, wc = (w & 1) * 64;
    f4 acc[2][4];
    #pragma unroll
    for (int i = 0; i < 2; ++i)
        #pragma unroll
        for (int j = 0; j < 4; ++j) acc[i][j] = (f4){0.f,0.f,0.f,0.f};

    #pragma unroll
    for (int kt = 0; kt < 256; kt += 64) {
        const int col16 = l & 7;
        #pragma unroll
        for (int i = 0; i < 2; ++i) {
            int c = w * 2 + i;
            int row = c * 8 + (l >> 3);
            size_t ga = (size_t)(m0 + row) * 256 + kt + col16 * 8;
            int loff = c * 1024 + l * 16;
            __builtin_amdgcn_global_load_lds(
                (const __attribute__((address_space(1))) void*)(Ahi + ga),
                (__attribute__((address_space(3))) void*)((char*)AsH + loff), 16, 0, 0);
            __builtin_amdgcn_global_load_lds(
                (const __attribute__((address_space(1))) void*)(Alo + ga),
                (__attribute__((address_space(3))) void*)((char*)AsL + loff), 16, 0, 0);
        }
        #pragma unroll
        for (int i = 0; i < 4; ++i) {
            int c = w * 4 + i;
            int row = c * 8 + (l >> 3);
            size_t gb = (size_t)(n0 + row) * 256 + kt + col16 * 8;
            int loff = c * 1024 + l * 16;
            __builtin_amdgcn_global_load_lds(
                (const __attribute__((address_space(1))) void*)(Bhi + gb),
                (__attribute__((address_space(3))) void*)((char*)BsH + loff), 16, 0, 0);
            __builtin_amdgcn_global_load_lds(
                (const __attribute__((address_space(1))) void*)(Blo + gb),
                (__attribute__((address_space(3))) void*)((char*)BsL + loff), 16, 0, 0);
        }
        __syncthreads();
        #pragma unroll
        for (int kk = 0; kk < 64; kk += 32) {
            short8 ah[2], al[2], bh[4], bl[4];
            #pragma unroll
            for (int mf = 0; mf < 2; ++mf) {
                int off = (wr + mf * 16 + (l & 15)) * 64 + kk + (l >> 4) * 8;
                ah[mf] = *(const short8*)(AsH + off);
                al[mf] = *(const short8*)(AsL + off);
            }
            #pragma unroll
            for (int nf = 0; nf < 4; ++nf) {
                int off = (wc + nf * 16 + (l & 15)) * 64 + kk + (l >> 4) * 8;
                bh[nf] = *(const short8*)(BsH + off);
                bl[nf] = *(const short8*)(BsL + off);
            }
            #pragma unroll
            for (int mf = 0; mf < 2; ++mf)
                #pragma unroll
                for (int nf = 0; nf < 4; ++nf) {
                    acc[mf][nf] = __builtin_amdgcn_mfma_f32_16x16x32_bf16(ah[mf], bh[nf], acc[mf][nf], 0, 0, 0);
                    acc[mf][nf] = __builtin_amdgcn_mfma_f32_16x16x32_bf16(al[mf], bh[nf], acc[mf][nf], 0, 0, 0);
                    acc[mf][nf] = __builtin_amdgcn_mfma_f32_16x16x32_bf16(ah[mf], bl[nf], acc[mf][nf], 0, 0, 0);
                }
        }
        __syncthreads();
    }
    #pragma unroll
    for (int nf = 0; nf < 4; ++nf) {
        int col = n0 + wc + nf * 16 + (l & 15);
        float bv = bias[col];
        #pragma unroll
        for (int mf = 0; mf < 2; ++mf) {
            int mrow = m0 + wr + mf * 16 + (l >> 4) * 4;
            #pragma unroll
            for (int q2 = 0; q2 < 4; ++q2) {
                float v = acc[mf][nf][q2] + bv;
                int m = mrow + q2;
                if (col < ncol_gh) {
                    gh[(size_t)m * 768 + col] = v;
                } else {
                    int c2 = col - ncol_gh;
                    if (c2 < VCD && lem)
                        lem[(size_t)m * (LMAXD * VCD) + c2] = v;
                }
            }
        }
    }
}

// ============ fallback argmax + GRU update (R13, proven) ============
__global__ __launch_bounds__(256)
void argupd_k(const float* __restrict__ gh, const float* __restrict__ git,
              const float* __restrict__ lem,
              ushort* __restrict__ hhi, ushort* __restrict__ hlo)
{
    const int bid = blockIdx.x;
    const int x = bid & 7, r = bid >> 3;
    const int i = r >> 6, jrow = r & 63;
    const int n = ((x + (i << 3)) << 6) + jrow;
    const int tid = threadIdx.x;
    __shared__ float sv[4];
    __shared__ int   si[4];
    __shared__ int   sprev;
    if (lem) {
        float v = (tid < VCD) ? lem[(size_t)n * (LMAXD * VCD) + tid] : -3.4e38f;
        int bi = tid;
        #pragma unroll
        for (int d = 1; d < 64; d <<= 1) {
            float ov = __shfl_xor(v, d);
            int   oi = __shfl_xor(bi, d);
            if (ov > v || (ov == v && oi < bi)) { v = ov; bi = oi; }
        }
        if ((tid & 63) == 0) { sv[tid >> 6] = v; si[tid >> 6] = bi; }
        __syncthreads();
        if (tid == 0) {
            float b = sv[0]; int bi2 = si[0];
            #pragma unroll
            for (int t2 = 1; t2 < 4; ++t2)
                if (sv[t2] > b || (sv[t2] == b && si[t2] < bi2)) { b = sv[t2]; bi2 = si[t2]; }
            sprev = bi2;
        }
    } else if (tid == 0) sprev = 3;
    __syncthreads();
    const int prev = sprev;
    const int j = tid;
    const float* g  = gh + (size_t)n * 768;
    const float* gi = git + (size_t)prev * 768;
    float rg = sigf(gi[j] + g[j]);
    float z  = sigf(gi[256 + j] + g[256 + j]);
    float nn = tanhf(gi[512 + j] + rg * g[512 + j]);
    size_t o = (size_t)n * HH + j;
    float hold = ub_f(hhi[o]) + ub_f(hlo[o]);
    float hv = (1.0f - z) * nn + z * hold;
    ushort hi = bhi_u(hv);
    hhi[o] = hi;
    hlo[o] = bhi_u(hv - ub_f(hi));
}

// ============ char-CNN MFMA ============
__global__ __launch_bounds__(256)
void conv_k(const ushort* __restrict__ cehi, const ushort* __restrict__ celo,
            const ushort* __restrict__ wre, const float* __restrict__ conv_b,
            float* __restrict__ enc_in)
{
    __shared__ __align__(16) ushort Bs[2 * 64 * 192];
    const int tid = threadIdx.x;
    for (int i = tid; i < 2 * 64 * 192 / 8; i += 256)
        ((uint4*)Bs)[i] = ((const uint4*)wre)[i];
    __syncthreads();
    const int w = tid >> 6, l = tid & 63;
    const int p = l & 15, g = l >> 4;
    const int base = (blockIdx.x * 4 + w) * 8;
    for (int wi = 0; wi < 8; ++wi) {
        int n = base + wi;
        short8 ahi[6], alo[6];
        #pragma unroll
        for (int kt = 0; kt < 6; ++kt) {
            int t = kt >> 1;
            int e0 = (kt & 1) * 32 + g * 8;
            int rl = p + t - 1;
            bool val = (rl >= 0 && rl < 16);
            size_t off = (size_t)(n * 16 + rl) * 64 + e0;
            short8 z = (short8){0,0,0,0,0,0,0,0};
            ahi[kt] = val ? *(const short8*)(cehi + off) : z;
            alo[kt] = val ? *(const short8*)(celo + off) : z;
        }
        f4 acc[4];
        #pragma unroll
        for (int nf = 0; nf < 4; ++nf) acc[nf] = (f4){0.f,0.f,0.f,0.f};
        #pragma unroll
        for (int kt = 0; kt < 6; ++kt) {
            #pragma unroll
            for (int nf = 0; nf < 4; ++nf) {
                int boff = (nf * 16 + (l & 15)) * 192 + kt * 32 + g * 8;
                short8 bh = *(const short8*)(Bs + boff);
                short8 bl = *(const short8*)(Bs + 12288 + boff);
                acc[nf] = __builtin_amdgcn_mfma_f32_16x16x32_bf16(ahi[kt], bh, acc[nf], 0, 0, 0);
                acc[nf] = __builtin_amdgcn_mfma_f32_16x16x32_bf16(alo[kt], bh, acc[nf], 0, 0, 0);
                acc[nf] = __builtin_amdgcn_mfma_f32_16x16x32_bf16(ahi[kt], bl, acc[nf], 0, 0, 0);
            }
        }
        #pragma unroll
        for (int nf = 0; nf < 4; ++nf) {
            float m = fmaxf(fmaxf(acc[nf][0], acc[nf][1]), fmaxf(acc[nf][2], acc[nf][3]));
            m = fmaxf(m, __shfl_xor(m, 16));
            m = fmaxf(m, __shfl_xor(m, 32));
            if (l < 16) {
                int c = nf * 16 + l;
                enc_in[(size_t)n * DIN + 128 + c] = fmaxf(0.0f, m + conv_b[c]);
            }
        }
    }
}

// ============ prep kernels ============
__global__ void repack192_k(const float* __restrict__ w, __hip_bfloat16* __restrict__ wre)
{
    int idx = blockIdx.x * 256 + threadIdx.x;
    if (idx >= 64 * 192) return;
    int kk = idx % 192, c = idx / 192;
    int t = kk >> 6, e = kk & 63;
    float v = (e < 48) ? w[(c * 48 + e) * 3 + t] : 0.0f;
    __hip_bfloat16 hi = __float2bfloat16(v);
    wre[idx] = hi;
    wre[64 * 192 + idx] = __float2bfloat16(v - __bfloat162float(hi));
}

__global__ void ce64_k(const int* __restrict__ char_ids, const float* __restrict__ char_emb,
                       __hip_bfloat16* __restrict__ hi, __hip_bfloat16* __restrict__ lo)
{
    size_t idx = (size_t)blockIdx.x * 256 + threadIdx.x;
    if (idx >= (size_t)NROWS * CLW * 64) return;
    int e = idx & 63;
    size_t r = idx >> 6;
    float v = (e < 48) ? char_emb[(size_t)char_ids[r] * CEw + e] : 0.0f;
    __hip_bfloat16 h = __float2bfloat16(v);
    hi[idx] = h;
    lo[idx] = __float2bfloat16(v - __bfloat162float(h));
}

__global__ void wv_k(const int* __restrict__ wid, const float* __restrict__ wemb,
                     float* __restrict__ enc_in)
{
    size_t idx = (size_t)blockIdx.x * 256 + threadIdx.x;
    if (idx >= (size_t)NROWS * 128) return;
    int e = idx & 127; size_t n = idx >> 7;
    enc_in[n * DIN + e] = wemb[(size_t)wid[n] * 128 + e];
}

__global__ void eisplit_k(const float* __restrict__ x, __hip_bfloat16* __restrict__ hi,
                          __hip_bfloat16* __restrict__ lo)
{
    size_t idx = (size_t)blockIdx.x * 256 + threadIdx.x;
    if (idx >= (size_t)NROWS * DIN) return;
    float v = x[idx];
    __hip_bfloat16 h = __float2bfloat16(v);
    hi[idx] = h;
    lo[idx] = __float2bfloat16(v - __bfloat162float(h));
}

__global__ void wsplit_k(const float* __restrict__ W, __hip_bfloat16* __restrict__ out,
                         int rows, int rowsPad, int K)
{
    int idx = blockIdx.x * 256 + threadIdx.x;
    if (idx >= rowsPad * K) return;
    int r = idx / K, k = idx - r * K;
    float v = (r < rows) ? W[(size_t)r * K + k] : 0.0f;
    __hip_bfloat16 hi = __float2bfloat16(v);
    out[idx] = hi;
    out[rowsPad * K + idx] = __float2bfloat16(v - __bfloat162float(hi));
}

__global__ void cmbsplit_k(const float* __restrict__ whh, const float* __restrict__ proj,
                           const float* __restrict__ bhh, const float* __restrict__ pb,
                           __hip_bfloat16* __restrict__ out, float* __restrict__ cbias)
{
    int idx = blockIdx.x * 256 + threadIdx.x;
    if (idx >= 1024 * 256) return;
    int r = idx >> 8, k = idx & 255;
    float v = (r < 768) ? whh[(size_t)r * 256 + k] : ((r < 968) ? proj[(size_t)(r - 768) * 256 + k] : 0.0f);
    __hip_bfloat16 hi = __float2bfloat16(v);
    out[idx] = hi;
    out[1024 * 256 + idx] = __float2bfloat16(v - __bfloat162float(hi));
    if (idx < 1024)
        cbias[idx] = (idx < 768) ? bhh[idx] : ((idx < 968) ? pb[idx - 768] : 0.0f);
}

__global__ void whht_k(const float* __restrict__ fw, const float* __restrict__ bw,
                       float* __restrict__ out)
{
    int idx = blockIdx.x * 256 + threadIdx.x;
    if (idx >= 131072) return;
    int q = idx & 3, j = (idx >> 2) & 127, k = (idx >> 9) & 127, d = idx >> 16;
    const float* w = d ? bw : fw;
    out[idx] = w[(size_t)(q * 128 + j) * 128 + k];
}

__global__ void gitab_k(const float* __restrict__ lemb, const float* __restrict__ wih,
                        const float* __restrict__ bih, float* __restrict__ git)
{
    int idx = blockIdx.x * 256 + threadIdx.x;
    if (idx >= VCD * 768) return;
    int g = idx % 768, v = idx / 768;
    float s = bih[g];
    #pragma unroll
    for (int k = 0; k < CEw; ++k) s = fmaf(lemb[v * CEw + k], wih[(size_t)g * CEw + k], s);
    git[idx] = s;
}

// ============ BiLSTM recurrence ============
__global__ __launch_bounds__(1024, 4)
void lstm_k(const float* __restrict__ gi2, const float* __restrict__ whht,
            __hip_bfloat16* __restrict__ enc_hi, __hip_bfloat16* __restrict__ enc_lo)
{
    const int dir = blockIdx.x >> 6, b = blockIdx.x & 63;
    const int tid = threadIdx.x;
    const int j = tid & 127, q = tid >> 7;
    const float* gi = gi2 + (size_t)dir * NROWS * 512;
    const f4* wt = (const f4*)(whht + (size_t)dir * 65536);
    f4 wreg[16];
    #pragma unroll
    for (int kk = 0; kk < 16; ++kk) wreg[kk] = wt[(q * 16 + kk) * 128 + j];
    __shared__ float hbuf[128];
    __shared__ f4 part[8][128];
    float c = 0.0f;
    if (tid < 128) hbuf[tid] = 0.0f;
    float nai = 0.f, naf = 0.f, nag = 0.f, nao = 0.f;
    if (q == 0) {
        int t0 = dir ? (TSEQ - 1) : 0;
        const float* gr = gi + ((size_t)b * TSEQ + t0) * 512;
        nai = gr[j]; naf = gr[128 + j]; nag = gr[256 + j]; nao = gr[384 + j];
    }
    __syncthreads();
    for (int s = 0; s < TSEQ; ++s) {
        int t = dir ? (TSEQ - 1 - s) : s;
        size_t n = (size_t)b * TSEQ + t;
        float ai = nai, af = naf, ag = nag, ao = nao;
        const f4* hb = (const f4*)(hbuf + q * 16);
        f4 hh[4] = {hb[0], hb[1], hb[2], hb[3]};
        f4 p = (f4){0.f,0.f,0.f,0.f};
        #pragma unroll
        for (int kk = 0; kk < 16; ++kk) {
            float hv = hh[kk >> 2][kk & 3];
            p.x = fmaf(wreg[kk].x, hv, p.x);
            p.y = fmaf(wreg[kk].y, hv, p.y);
            p.z = fmaf(wreg[kk].z, hv, p.z);
            p.w = fmaf(wreg[kk].w, hv, p.w);
        }
        part[q][j] = p;
        __syncthreads();
        if (q == 0) {
            f4 sum = part[0][j];
            #pragma unroll
            for (int qq = 1; qq < 8; ++qq) {
                f4 pp = part[qq][j];
                sum.x += pp.x; sum.y += pp.y; sum.z += pp.z; sum.w += pp.w;
            }
            ai += sum.x; af += sum.y; ag += sum.z; ao += sum.w;
            c = sigf(af) * c + sigf(ai) * tanhf(ag);
            float h = sigf(ao) * tanhf(c);
            hbuf[j] = h;
            size_t o = n * HH + dir * 128 + j;
            __hip_bfloat16 hi = __float2bfloat16(h);
            enc_hi[o] = hi;
            enc_lo[o] = __float2bfloat16(h - __bfloat162float(hi));
            if (s + 1 < TSEQ) {
                int t2 = dir ? (TSEQ - 2 - s) : (s + 1);
                const float* gr2 = gi + ((size_t)b * TSEQ + t2) * 512;
                nai = gr2[j]; naf = gr2[128 + j]; nag = gr2[256 + j]; nao = gr2[384 + j];
            }
        }
        __syncthreads();
    }
}

extern "C" void kernel_launch(void* const* d_in, const int* in_sizes, int n_in,
                              void* d_out, int out_size, void* d_ws, size_t ws_size,
                              hipStream_t stream)
{
    const int*   word_ids = (const int*)d_in[0];
    const int*   char_ids = (const int*)d_in[1];
    const float* word_emb = (const float*)d_in[2];
    const float* char_emb = (const float*)d_in[3];
    const float* conv_w   = (const float*)d_in[4];
    const float* conv_b   = (const float*)d_in[5];
    const float* fw_wih   = (const float*)d_in[6];
    const float* fw_whh   = (const float*)d_in[7];
    const float* fw_b     = (const float*)d_in[8];
    const float* bw_wih   = (const float*)d_in[9];
    const float* bw_whh   = (const float*)d_in[10];
    const float* bw_b     = (const float*)d_in[11];
    const float* tag_w    = (const float*)d_in[12];
    const float* tag_b    = (const float*)d_in[13];
    const float* lemma_emb= (const float*)d_in[14];
    const float* init_w   = (const float*)d_in[15];
    const float* init_b   = (const float*)d_in[16];
    const float* gru_wih  = (const float*)d_in[17];
    const float* gru_whh  = (const float*)d_in[18];
    const float* gru_bih  = (const float*)d_in[19];
    const float* gru_bhh  = (const float*)d_in[20];
    const float* proj_w   = (const float*)d_in[21];
    const float* proj_b   = (const float*)d_in[22];

    char* ws = (char*)d_ws;
    float* out_tag = (float*)d_out;
    float* out_lem = out_tag + (size_t)NROWS * NTAGS;

    const bool fused = (ws_size >= 51998720ull);

    // ---- pointer sets for both layouts ----
    float *enc_in, *gi2, *whht, *git, *cmb_bias, *hdec_scratch;
    __hip_bfloat16 *ce_hi, *ce_lo, *ei_hi, *ei_lo, *enc_hi, *enc_lo;
    __hip_bfloat16 *wre_ext, *wfw_ext, *wbw_ext, *tag_ext, *init_ext, *cmb_ext;
    ushort *b0_hi, *b0_lo, *b1_hi, *b1_lo;
    float *ghA, *ghB;

    if (fused) {
        ce_hi = (__hip_bfloat16*)(ws + 0);
        ce_lo = (__hip_bfloat16*)(ws + 12582912);
        enc_in = (float*)(ws + 25165824);
        wre_ext = (__hip_bfloat16*)(ws + 29884416);
        wfw_ext = (__hip_bfloat16*)(ws + 29933568);
        wbw_ext = (__hip_bfloat16*)(ws + 30326784);
        ei_hi = (__hip_bfloat16*)(ws + 30720000);
        ei_lo = (__hip_bfloat16*)(ws + 33079296);
        whht = (float*)(ws + 35438592);
        tag_ext = (__hip_bfloat16*)(ws + 35962880);
        init_ext = (__hip_bfloat16*)(ws + 36618240);
        gi2 = (float*)(ws + 0);
        enc_hi = (__hip_bfloat16*)(ws + 25165824);
        enc_lo = (__hip_bfloat16*)(ws + 28311552);
        hdec_scratch = (float*)(ws + 0);
        ghA = (float*)(ws + 0);
        ghB = (float*)(ws + 18874368);
        b0_hi = (ushort*)(ws + 37748736);
        b0_lo = (ushort*)(ws + 40894464);
        b1_hi = (ushort*)(ws + 44040192);
        b1_lo = (ushort*)(ws + 47185920);
        git = (float*)(ws + 50331648);
        cmb_ext = (__hip_bfloat16*)(ws + 50946048);
        cmb_bias = (float*)(ws + 51994624);
    } else {
        // R13 layout (proven)
        enc_in = (float*)(ws);
        ei_hi = (__hip_bfloat16*)(ws + 4718592);
        ei_lo = (__hip_bfloat16*)(ws + 7077888);
        enc_hi = (__hip_bfloat16*)(ws);
        enc_lo = (__hip_bfloat16*)(ws + 3145728);
        char* R1 = ws + 9437184;
        ce_hi = (__hip_bfloat16*)R1;
        ce_lo = (__hip_bfloat16*)(R1 + 12582912);
        gi2 = (float*)R1;
        ghA = (float*)R1;                           // single gh
        ghB = ghA;
        cmb_ext = (__hip_bfloat16*)(R1 + 18874368);
        cmb_bias = (float*)(R1 + 18874368 + 1048576);
        hdec_scratch = (float*)(ws + 34603008);
        b0_hi = (ushort*)(ws + 40894464);
        b0_lo = (ushort*)(ws + 44040192);
        b1_hi = b0_hi; b1_lo = b0_lo;               // no ping-pong in fallback
        git = (float*)(ws + 47185920);
        whht = (float*)(ws + 47800320);
        wre_ext = (__hip_bfloat16*)(ws + 48349184);
        wfw_ext = (__hip_bfloat16*)(ws + 48398336);
        wbw_ext = (__hip_bfloat16*)(ws + 48791552);
        tag_ext = (__hip_bfloat16*)(ws + 49184768);
        init_ext = (__hip_bfloat16*)(ws + 49840128);
    }

    // ---- front-end ----
    repack192_k<<<48, 256, 0, stream>>>(conv_w, wre_ext);
    ce64_k<<<24576, 256, 0, stream>>>(char_ids, char_emb, ce_hi, ce_lo);
    wv_k<<<3072, 256, 0, stream>>>(word_ids, word_emb, enc_in);
    conv_k<<<192, 256, 0, stream>>>((const ushort*)ce_hi, (const ushort*)ce_lo,
                                    (const ushort*)wre_ext, conv_b, enc_in);
    eisplit_k<<<4608, 256, 0, stream>>>(enc_in, ei_hi, ei_lo);
    wsplit_k<<<384, 256, 0, stream>>>(fw_wih, wfw_ext, 512, 512, 192);
    wsplit_k<<<384, 256, 0, stream>>>(bw_wih, wbw_ext, 512, 512, 192);

    // ---- LSTM input gates, then recurrence ----
    gemm3_k<0,0,192><<<dim3(48,4), 256, 0, stream>>>((const ushort*)ei_hi, (const ushort*)ei_lo,
        (const ushort*)wfw_ext, (const ushort*)(wfw_ext + 512*192), fw_b, gi2,
        nullptr, nullptr, 512, 512);
    gemm3_k<0,0,192><<<dim3(48,4), 256, 0, stream>>>((const ushort*)ei_hi, (const ushort*)ei_lo,
        (const ushort*)wbw_ext, (const ushort*)(wbw_ext + 512*192), bw_b, gi2 + (size_t)NROWS*512,
        nullptr, nullptr, 512, 512);
    whht_k<<<512, 256, 0, stream>>>(fw_whh, bw_whh, whht);
    lstm_k<<<128, 1024, 0, stream>>>(gi2, whht, enc_hi, enc_lo);

    // ---- heads + decode prep ----
    cmbsplit_k<<<1024, 256, 0, stream>>>(gru_whh, proj_w, gru_bhh, proj_b, cmb_ext, cmb_bias);
    wsplit_k<<<640, 256, 0, stream>>>(tag_w, tag_ext, 600, 640, 256);
    wsplit_k<<<256, 256, 0, stream>>>(init_w, init_ext, 256, 256, 256);
    gitab_k<<<600, 256, 0, stream>>>(lemma_emb, gru_wih, gru_bih, git);
    gemm3_k<0,0,256><<<dim3(48,5), 256, 0, stream>>>((const ushort*)enc_hi, (const ushort*)enc_lo,
        (const ushort*)tag_ext, (const ushort*)(tag_ext + 640*256), tag_b, out_tag,
        nullptr, nullptr, NTAGS, NTAGS);
    gemm3_k<1,1,256><<<dim3(48,2), 256, 0, stream>>>((const ushort*)enc_hi, (const ushort*)enc_lo,
        (const ushort*)init_ext, (const ushort*)(init_ext + 256*256), init_b, hdec_scratch,
        b0_hi, b0_lo, 256, 256);

    const ushort* cmb_hi = (const ushort*)cmb_ext;
    const ushort* cmb_lo = cmb_hi + 1024 * 256;

    if (fused) {
        // ---- fused decode: 25 dispatches ----
        float* ghbuf[2] = {ghA, ghB};
        ushort* hb_hi[2] = {b0_hi, b1_hi};
        ushort* hb_lo[2] = {b0_lo, b1_lo};
        for (int t = 0; t <= 24; ++t) {
            float* ghW = ghbuf[t & 1];
            const float* ghR = ghbuf[(t ^ 1) & 1];
            int rp = (t == 0) ? 0 : ((t - 1) & 1);
            int wp = t & 1;
            dim3 grid = (t == 0) ? dim3(192, 6) : ((t == 24) ? dim3(192, 2) : dim3(192, 8));
            int n0base = (t == 24) ? 768 : 0;
            dec_k<<<grid, 256, 0, stream>>>(ghW, ghR,
                hb_hi[rp], hb_lo[rp], hb_hi[wp], hb_lo[wp],
                git, cmb_hi, cmb_lo, cmb_bias, out_lem, t, n0base);
        }
    } else {
        // ---- fallback decode (R13) ----
        float* gh = ghA;
        for (int s = 0; s < LMAXD; ++s) {
            float* lem = (s > 0) ? (out_lem + (size_t)(s - 1) * VCD) : nullptr;
            gemmC_k<<<dim3(96,8), 256, 0, stream>>>((const ushort*)b0_hi, (const ushort*)b0_lo,
                cmb_hi, cmb_lo, cmb_bias, gh, lem, 768);
            argupd_k<<<NROWS, 256, 0, stream>>>(gh, git, lem, b0_hi, b0_lo);
        }
        gemmC_k<<<dim3(96,2), 256, 0, stream>>>((const ushort*)b0_hi, (const ushort*)b0_lo,
            cmb_hi + 768 * 256, cmb_lo + 768 * 256, cmb_bias + 768,
            nullptr, out_lem + (size_t)(LMAXD - 1) * VCD, 0);
    }
}

// Round 15
// 897.252 us; speedup vs baseline: 1.9201x; 1.9201x over previous
//
#include <hip/hip_runtime.h>
#include <hip/hip_bf16.h>
#include <math.h>

typedef float f4 __attribute__((ext_vector_type(4)));
typedef __attribute__((ext_vector_type(8))) short short8;

#define NTAGS 600
#define CEw   48
#define HH    256
#define TSEQ  96
#define CLW   16
#define LMAXD 24
#define NROWS 6144
#define DIN   192
#define VCD   200

__device__ __forceinline__ float sigf(float x){ return 1.0f/(1.0f+expf(-x)); }
__device__ __forceinline__ ushort bhi_u(float v){ __hip_bfloat16 h = __float2bfloat16(v); return *(ushort*)&h; }
__device__ __forceinline__ float ub_f(ushort u){ __hip_bfloat16 h = *(__hip_bfloat16*)&u; return __bfloat162float(h); }

// ============ generalized MFMA 3-term GEMM (per-segment LDS staging; proven) ============
template<int ACT, int HS, int KK>
__global__ __launch_bounds__(256)
void gemm3_k(const ushort* __restrict__ Ahi, const ushort* __restrict__ Alo,
             const ushort* __restrict__ Bhi, const ushort* __restrict__ Blo,
             const float* __restrict__ bias, float* __restrict__ C,
             ushort* __restrict__ Hhi, ushort* __restrict__ Hlo,
             int Nc, int ldC)
{
    __shared__ __align__(16) ushort As[128 * 64];
    __shared__ __align__(16) ushort Bs[128 * 64];
    const int tid = threadIdx.x;
    const int m0 = blockIdx.x * 128;
    const int n0 = blockIdx.y * 128;
    const int w = tid >> 6, l = tid & 63;
    const int wr = (w >> 1) * 64, wc = (w & 1) * 64;
    f4 acc[4][4];
    #pragma unroll
    for (int i = 0; i < 4; ++i)
        #pragma unroll
        for (int j = 0; j < 4; ++j) acc[i][j] = (f4){0.f,0.f,0.f,0.f};

    #pragma unroll
    for (int seg = 0; seg < 3; ++seg) {
        const ushort* Ap = (seg == 1) ? Alo : Ahi;
        const ushort* Bp = (seg == 2) ? Blo : Bhi;
        #pragma unroll
        for (int kt = 0; kt < KK; kt += 64) {
            #pragma unroll
            for (int i = 0; i < 4; ++i) {
                int c = w * 4 + i;
                int row = c * 8 + (l >> 3);
                int col16 = l & 7;
                __builtin_amdgcn_global_load_lds(
                    (const __attribute__((address_space(1))) void*)(Ap + (size_t)(m0 + row) * KK + kt + col16 * 8),
                    (__attribute__((address_space(3))) void*)((char*)As + c * 1024 + l * 16), 16, 0, 0);
                __builtin_amdgcn_global_load_lds(
                    (const __attribute__((address_space(1))) void*)(Bp + (size_t)(n0 + row) * KK + kt + col16 * 8),
                    (__attribute__((address_space(3))) void*)((char*)Bs + c * 1024 + l * 16), 16, 0, 0);
            }
            __syncthreads();
            #pragma unroll
            for (int kk = 0; kk < 64; kk += 32) {
                short8 a[4], b[4];
                #pragma unroll
                for (int mf = 0; mf < 4; ++mf)
                    a[mf] = *(const short8*)(As + (wr + mf * 16 + (l & 15)) * 64 + kk + (l >> 4) * 8);
                #pragma unroll
                for (int nf = 0; nf < 4; ++nf)
                    b[nf] = *(const short8*)(Bs + (wc + nf * 16 + (l & 15)) * 64 + kk + (l >> 4) * 8);
                #pragma unroll
                for (int mf = 0; mf < 4; ++mf)
                    #pragma unroll
                    for (int nf = 0; nf < 4; ++nf)
                        acc[mf][nf] = __builtin_amdgcn_mfma_f32_16x16x32_bf16(a[mf], b[nf], acc[mf][nf], 0, 0, 0);
            }
            __syncthreads();
        }
    }
    #pragma unroll
    for (int nf = 0; nf < 4; ++nf) {
        int n = n0 + wc + nf * 16 + (l & 15);
        if (n >= Nc) continue;
        float bv = bias[n];
        #pragma unroll
        for (int mf = 0; mf < 4; ++mf) {
            int mrow = m0 + wr + mf * 16 + (l >> 4) * 4;
            #pragma unroll
            for (int q2 = 0; q2 < 4; ++q2) {
                float v = acc[mf][nf][q2] + bv;
                if (ACT == 1) v = tanhf(v);
                size_t o = (size_t)(mrow + q2) * ldC + n;
                C[o] = v;
                if (HS) {
                    ushort hi = bhi_u(v);
                    Hhi[o] = hi;
                    Hlo[o] = bhi_u(v - ub_f(hi));
                }
            }
        }
    }
}

// ============ decode GEMM, 64x128 tile + LDS staging (proven R11/R13) ============
__global__ __launch_bounds__(256)
void gemmC_k(const ushort* __restrict__ Ahi, const ushort* __restrict__ Alo,
             const ushort* __restrict__ Bhi, const ushort* __restrict__ Blo,
             const float* __restrict__ bias,
             float* __restrict__ gh, float* __restrict__ lem, int ncol_gh)
{
    __shared__ __align__(16) ushort AsH[64 * 64];
    __shared__ __align__(16) ushort AsL[64 * 64];
    __shared__ __align__(16) ushort BsH[128 * 64];
    __shared__ __align__(16) ushort BsL[128 * 64];
    const int tid = threadIdx.x;
    const int m0 = blockIdx.x * 64;
    const int n0 = blockIdx.y * 128;
    const int w = tid >> 6, l = tid & 63;
    const int wr = (w >> 1) * 32, wc = (w & 1) * 64;
    f4 acc[2][4];
    #pragma unroll
    for (int i = 0; i < 2; ++i)
        #pragma unroll
        for (int j = 0; j < 4; ++j) acc[i][j] = (f4){0.f,0.f,0.f,0.f};

    #pragma unroll
    for (int kt = 0; kt < 256; kt += 64) {
        const int col16 = l & 7;
        #pragma unroll
        for (int i = 0; i < 2; ++i) {
            int c = w * 2 + i;
            int row = c * 8 + (l >> 3);
            size_t ga = (size_t)(m0 + row) * 256 + kt + col16 * 8;
            int loff = c * 1024 + l * 16;
            __builtin_amdgcn_global_load_lds(
                (const __attribute__((address_space(1))) void*)(Ahi + ga),
                (__attribute__((address_space(3))) void*)((char*)AsH + loff), 16, 0, 0);
            __builtin_amdgcn_global_load_lds(
                (const __attribute__((address_space(1))) void*)(Alo + ga),
                (__attribute__((address_space(3))) void*)((char*)AsL + loff), 16, 0, 0);
        }
        #pragma unroll
        for (int i = 0; i < 4; ++i) {
            int c = w * 4 + i;
            int row = c * 8 + (l >> 3);
            size_t gb = (size_t)(n0 + row) * 256 + kt + col16 * 8;
            int loff = c * 1024 + l * 16;
            __builtin_amdgcn_global_load_lds(
                (const __attribute__((address_space(1))) void*)(Bhi + gb),
                (__attribute__((address_space(3))) void*)((char*)BsH + loff), 16, 0, 0);
            __builtin_amdgcn_global_load_lds(
                (const __attribute__((address_space(1))) void*)(Blo + gb),
                (__attribute__((address_space(3))) void*)((char*)BsL + loff), 16, 0, 0);
        }
        __syncthreads();
        #pragma unroll
        for (int kk = 0; kk < 64; kk += 32) {
            short8 ah[2], al[2], bh[4], bl[4];
            #pragma unroll
            for (int mf = 0; mf < 2; ++mf) {
                int off = (wr + mf * 16 + (l & 15)) * 64 + kk + (l >> 4) * 8;
                ah[mf] = *(const short8*)(AsH + off);
                al[mf] = *(const short8*)(AsL + off);
            }
            #pragma unroll
            for (int nf = 0; nf < 4; ++nf) {
                int off = (wc + nf * 16 + (l & 15)) * 64 + kk + (l >> 4) * 8;
                bh[nf] = *(const short8*)(BsH + off);
                bl[nf] = *(const short8*)(BsL + off);
            }
            #pragma unroll
            for (int mf = 0; mf < 2; ++mf)
                #pragma unroll
                for (int nf = 0; nf < 4; ++nf) {
                    acc[mf][nf] = __builtin_amdgcn_mfma_f32_16x16x32_bf16(ah[mf], bh[nf], acc[mf][nf], 0, 0, 0);
                    acc[mf][nf] = __builtin_amdgcn_mfma_f32_16x16x32_bf16(al[mf], bh[nf], acc[mf][nf], 0, 0, 0);
                    acc[mf][nf] = __builtin_amdgcn_mfma_f32_16x16x32_bf16(ah[mf], bl[nf], acc[mf][nf], 0, 0, 0);
                }
        }
        __syncthreads();
    }
    #pragma unroll
    for (int nf = 0; nf < 4; ++nf) {
        int col = n0 + wc + nf * 16 + (l & 15);
        float bv = bias[col];
        #pragma unroll
        for (int mf = 0; mf < 2; ++mf) {
            int mrow = m0 + wr + mf * 16 + (l >> 4) * 4;
            #pragma unroll
            for (int q2 = 0; q2 < 4; ++q2) {
                float v = acc[mf][nf][q2] + bv;
                int m = mrow + q2;
                if (col < ncol_gh) {
                    gh[(size_t)m * 768 + col] = v;
                } else {
                    int c2 = col - ncol_gh;
                    if (c2 < VCD && lem)
                        lem[(size_t)m * (LMAXD * VCD) + c2] = v;
                }
            }
        }
    }
}

// ============ fused argmax(prev logits) + GRU update; h state in bf16 planes (proven R13) ===
__global__ __launch_bounds__(256)
void argupd_k(const float* __restrict__ gh, const float* __restrict__ git,
              const float* __restrict__ lem,
              ushort* __restrict__ hhi, ushort* __restrict__ hlo)
{
    const int bid = blockIdx.x;
    const int x = bid & 7, r = bid >> 3;
    const int i = r >> 6, jrow = r & 63;
    const int n = ((x + (i << 3)) << 6) + jrow;
    const int tid = threadIdx.x;
    __shared__ float sv[4];
    __shared__ int   si[4];
    __shared__ int   sprev;
    if (lem) {
        float v = (tid < VCD) ? lem[(size_t)n * (LMAXD * VCD) + tid] : -3.4e38f;
        int bi = tid;
        #pragma unroll
        for (int d = 1; d < 64; d <<= 1) {
            float ov = __shfl_xor(v, d);
            int   oi = __shfl_xor(bi, d);
            if (ov > v || (ov == v && oi < bi)) { v = ov; bi = oi; }
        }
        if ((tid & 63) == 0) { sv[tid >> 6] = v; si[tid >> 6] = bi; }
        __syncthreads();
        if (tid == 0) {
            float b = sv[0]; int bi2 = si[0];
            #pragma unroll
            for (int t2 = 1; t2 < 4; ++t2)
                if (sv[t2] > b || (sv[t2] == b && si[t2] < bi2)) { b = sv[t2]; bi2 = si[t2]; }
            sprev = bi2;
        }
    } else if (tid == 0) sprev = 3;   // BOS
    __syncthreads();
    const int prev = sprev;
    const int j = tid;
    const float* g  = gh + (size_t)n * 768;
    const float* gi = git + (size_t)prev * 768;
    float rg = sigf(gi[j] + g[j]);
    float z  = sigf(gi[256 + j] + g[256 + j]);
    float nn = tanhf(gi[512 + j] + rg * g[512 + j]);
    size_t o = (size_t)n * HH + j;
    float hold = ub_f(hhi[o]) + ub_f(hlo[o]);
    float hv = (1.0f - z) * nn + z * hold;
    ushort hi = bhi_u(hv);
    hhi[o] = hi;
    hlo[o] = bhi_u(hv - ub_f(hi));
}

// ============ char-CNN MFMA with INLINE ce gather (replaces ce64_k + plane loads) ============
__global__ __launch_bounds__(256)
void conv_k(const int* __restrict__ char_ids, const float* __restrict__ char_emb,
            const ushort* __restrict__ wre, const float* __restrict__ conv_b,
            float* __restrict__ enc_in)
{
    __shared__ __align__(16) ushort Bs[2 * 64 * 192];
    const int tid = threadIdx.x;
    for (int i = tid; i < 2 * 64 * 192 / 8; i += 256)
        ((uint4*)Bs)[i] = ((const uint4*)wre)[i];
    __syncthreads();
    const int w = tid >> 6, l = tid & 63;
    const int p = l & 15, g = l >> 4;
    const int base = (blockIdx.x * 4 + w) * 8;
    for (int wi = 0; wi < 8; ++wi) {
        int n = base + wi;
        short8 ahi[6], alo[6];
        #pragma unroll
        for (int kt = 0; kt < 6; ++kt) {
            int t = kt >> 1;
            int e0 = (kt & 1) * 32 + g * 8;
            int rl = p + t - 1;
            bool val = (rl >= 0 && rl < 16) && (e0 < 48);
            short8 zh = (short8){0,0,0,0,0,0,0,0};
            short8 zl = zh;
            if (val) {
                int cid = char_ids[n * 16 + rl];
                const float* src = char_emb + (size_t)cid * CEw + e0;
                f4 v0 = *(const f4*)(src);
                f4 v1 = *(const f4*)(src + 4);
                #pragma unroll
                for (int i2 = 0; i2 < 4; ++i2) {
                    ushort h0 = bhi_u(v0[i2]);
                    ushort h1 = bhi_u(v1[i2]);
                    zh[i2] = (short)h0;
                    zh[i2 + 4] = (short)h1;
                    zl[i2] = (short)bhi_u(v0[i2] - ub_f(h0));
                    zl[i2 + 4] = (short)bhi_u(v1[i2] - ub_f(h1));
                }
            }
            ahi[kt] = zh;
            alo[kt] = zl;
        }
        f4 acc[4];
        #pragma unroll
        for (int nf = 0; nf < 4; ++nf) acc[nf] = (f4){0.f,0.f,0.f,0.f};
        #pragma unroll
        for (int kt = 0; kt < 6; ++kt) {
            #pragma unroll
            for (int nf = 0; nf < 4; ++nf) {
                int boff = (nf * 16 + (l & 15)) * 192 + kt * 32 + g * 8;
                short8 bh = *(const short8*)(Bs + boff);
                short8 bl = *(const short8*)(Bs + 12288 + boff);
                acc[nf] = __builtin_amdgcn_mfma_f32_16x16x32_bf16(ahi[kt], bh, acc[nf], 0, 0, 0);
                acc[nf] = __builtin_amdgcn_mfma_f32_16x16x32_bf16(alo[kt], bh, acc[nf], 0, 0, 0);
                acc[nf] = __builtin_amdgcn_mfma_f32_16x16x32_bf16(ahi[kt], bl, acc[nf], 0, 0, 0);
            }
        }
        #pragma unroll
        for (int nf = 0; nf < 4; ++nf) {
            float m = fmaxf(fmaxf(acc[nf][0], acc[nf][1]), fmaxf(acc[nf][2], acc[nf][3]));
            m = fmaxf(m, __shfl_xor(m, 16));
            m = fmaxf(m, __shfl_xor(m, 32));
            if (l < 16) {
                int c = nf * 16 + l;
                enc_in[(size_t)n * DIN + 128 + c] = fmaxf(0.0f, m + conv_b[c]);
            }
        }
    }
}

// ============ prep kernels ============
__global__ void repack192_k(const float* __restrict__ w, __hip_bfloat16* __restrict__ wre)
{
    int idx = blockIdx.x * 256 + threadIdx.x;
    if (idx >= 64 * 192) return;
    int kk = idx % 192, c = idx / 192;
    int t = kk >> 6, e = kk & 63;
    float v = (e < 48) ? w[(c * 48 + e) * 3 + t] : 0.0f;
    __hip_bfloat16 hi = __float2bfloat16(v);
    wre[idx] = hi;
    wre[64 * 192 + idx] = __float2bfloat16(v - __bfloat162float(hi));
}

__global__ void wv_k(const int* __restrict__ wid, const float* __restrict__ wemb,
                     float* __restrict__ enc_in)
{
    size_t idx = (size_t)blockIdx.x * 256 + threadIdx.x;
    if (idx >= (size_t)NROWS * 128) return;
    int e = idx & 127; size_t n = idx >> 7;
    enc_in[n * DIN + e] = wemb[(size_t)wid[n] * 128 + e];
}

__global__ void eisplit_k(const float* __restrict__ x, __hip_bfloat16* __restrict__ hi,
                          __hip_bfloat16* __restrict__ lo)
{
    size_t idx = (size_t)blockIdx.x * 256 + threadIdx.x;
    if (idx >= (size_t)NROWS * DIN) return;
    float v = x[idx];
    __hip_bfloat16 h = __float2bfloat16(v);
    hi[idx] = h;
    lo[idx] = __float2bfloat16(v - __bfloat162float(h));
}

__global__ void wsplit_k(const float* __restrict__ W, __hip_bfloat16* __restrict__ out,
                         int rows, int rowsPad, int K)
{
    int idx = blockIdx.x * 256 + threadIdx.x;
    if (idx >= rowsPad * K) return;
    int r = idx / K, k = idx - r * K;
    float v = (r < rows) ? W[(size_t)r * K + k] : 0.0f;
    __hip_bfloat16 hi = __float2bfloat16(v);
    out[idx] = hi;
    out[rowsPad * K + idx] = __float2bfloat16(v - __bfloat162float(hi));
}

// combined decode B: rows 0..767 = gru_whh, 768..967 = proj_w, 968..1023 = 0; + combined bias
__global__ void cmbsplit_k(const float* __restrict__ whh, const float* __restrict__ proj,
                           const float* __restrict__ bhh, const float* __restrict__ pb,
                           __hip_bfloat16* __restrict__ out, float* __restrict__ cbias)
{
    int idx = blockIdx.x * 256 + threadIdx.x;
    if (idx >= 1024 * 256) return;
    int r = idx >> 8, k = idx & 255;
    float v = (r < 768) ? whh[(size_t)r * 256 + k] : ((r < 968) ? proj[(size_t)(r - 768) * 256 + k] : 0.0f);
    __hip_bfloat16 hi = __float2bfloat16(v);
    out[idx] = hi;
    out[1024 * 256 + idx] = __float2bfloat16(v - __bfloat162float(hi));
    if (idx < 1024)
        cbias[idx] = (idx < 768) ? bhh[idx] : ((idx < 968) ? pb[idx - 768] : 0.0f);
}

// whhT4[dir][k][j][gate] f32, gates (i,f,g,o)
__global__ void whht_k(const float* __restrict__ fw, const float* __restrict__ bw,
                       float* __restrict__ out)
{
    int idx = blockIdx.x * 256 + threadIdx.x;
    if (idx >= 131072) return;
    int q = idx & 3, j = (idx >> 2) & 127, k = (idx >> 9) & 127, d = idx >> 16;
    const float* w = d ? bw : fw;
    out[idx] = w[(size_t)(q * 128 + j) * 128 + k];
}

__global__ void gitab_k(const float* __restrict__ lemb, const float* __restrict__ wih,
                        const float* __restrict__ bih, float* __restrict__ git)
{
    int idx = blockIdx.x * 256 + threadIdx.x;
    if (idx >= VCD * 768) return;
    int g = idx % 768, v = idx / 768;
    float s = bih[g];
    #pragma unroll
    for (int k = 0; k < CEw; ++k) s = fmaf(lemb[v * CEw + k], wih[(size_t)g * CEw + k], s);
    git[idx] = s;
}

// ============ BiLSTM recurrence: gate-parallel activations (3-phase) ============
__global__ __launch_bounds__(1024, 4)
void lstm_k(const float* __restrict__ gi2, const float* __restrict__ whht,
            __hip_bfloat16* __restrict__ enc_hi, __hip_bfloat16* __restrict__ enc_lo)
{
    const int dir = blockIdx.x >> 6, b = blockIdx.x & 63;
    const int tid = threadIdx.x;
    const int j = tid & 127, q = tid >> 7;
    const float* gi = gi2 + (size_t)dir * NROWS * 512;
    const f4* wt = (const f4*)(whht + (size_t)dir * 65536);
    f4 wreg[16];
    #pragma unroll
    for (int kk = 0; kk < 16; ++kk) wreg[kk] = wt[(q * 16 + kk) * 128 + j];
    __shared__ float hbuf[128];
    __shared__ f4 part[8][128];
    __shared__ float act[4][128];
    float c = 0.0f;
    if (tid < 128) hbuf[tid] = 0.0f;
    float gnext = 0.0f;
    if (q < 4) {
        int t0 = dir ? (TSEQ - 1) : 0;
        gnext = gi[((size_t)b * TSEQ + t0) * 512 + q * 128 + j];
    }
    __syncthreads();
    for (int s = 0; s < TSEQ; ++s) {
        int t = dir ? (TSEQ - 1 - s) : s;
        size_t n = (size_t)b * TSEQ + t;
        // phase 1: split-k partials (all 8 k-groups)
        const f4* hb = (const f4*)(hbuf + q * 16);
        f4 hh[4] = {hb[0], hb[1], hb[2], hb[3]};
        f4 p = (f4){0.f,0.f,0.f,0.f};
        #pragma unroll
        for (int kk = 0; kk < 16; ++kk) {
            float hv = hh[kk >> 2][kk & 3];
            p.x = fmaf(wreg[kk].x, hv, p.x);
            p.y = fmaf(wreg[kk].y, hv, p.y);
            p.z = fmaf(wreg[kk].z, hv, p.z);
            p.w = fmaf(wreg[kk].w, hv, p.w);
        }
        part[q][j] = p;
        __syncthreads();
        // phase 2: gate-parallel reduce + activation (q = gate 0..3), + gi prefetch
        if (q < 4) {
            f4 sv = part[0][j];
            #pragma unroll
            for (int qq = 1; qq < 8; ++qq) {
                f4 pp = part[qq][j];
                sv.x += pp.x; sv.y += pp.y; sv.z += pp.z; sv.w += pp.w;
            }
            float sum;
            if (q == 0)      sum = sv.x;
            else if (q == 1) sum = sv.y;
            else if (q == 2) sum = sv.z;
            else             sum = sv.w;
            float pre = gnext + sum;
            act[q][j] = (q == 2) ? tanhf(pre) : sigf(pre);
            if (s + 1 < TSEQ) {
                int t2 = dir ? (TSEQ - 2 - s) : (s + 1);
                gnext = gi[((size_t)b * TSEQ + t2) * 512 + q * 128 + j];
            }
        }
        __syncthreads();
        // phase 3: c/h update (q==0 only; 1 tanh)
        if (q == 0) {
            float ai_ = act[0][j], af_ = act[1][j], ag_ = act[2][j], ao_ = act[3][j];
            c = af_ * c + ai_ * ag_;
            float h = ao_ * tanhf(c);
            hbuf[j] = h;
            size_t o = n * HH + dir * 128 + j;
            __hip_bfloat16 hi = __float2bfloat16(h);
            enc_hi[o] = hi;
            enc_lo[o] = __float2bfloat16(h - __bfloat162float(hi));
        }
        __syncthreads();
    }
}

extern "C" void kernel_launch(void* const* d_in, const int* in_sizes, int n_in,
                              void* d_out, int out_size, void* d_ws, size_t ws_size,
                              hipStream_t stream)
{
    const int*   word_ids = (const int*)d_in[0];
    const int*   char_ids = (const int*)d_in[1];
    const float* word_emb = (const float*)d_in[2];
    const float* char_emb = (const float*)d_in[3];
    const float* conv_w   = (const float*)d_in[4];
    const float* conv_b   = (const float*)d_in[5];
    const float* fw_wih   = (const float*)d_in[6];
    const float* fw_whh   = (const float*)d_in[7];
    const float* fw_b     = (const float*)d_in[8];
    const float* bw_wih   = (const float*)d_in[9];
    const float* bw_whh   = (const float*)d_in[10];
    const float* bw_b     = (const float*)d_in[11];
    const float* tag_w    = (const float*)d_in[12];
    const float* tag_b    = (const float*)d_in[13];
    const float* lemma_emb= (const float*)d_in[14];
    const float* init_w   = (const float*)d_in[15];
    const float* init_b   = (const float*)d_in[16];
    const float* gru_wih  = (const float*)d_in[17];
    const float* gru_whh  = (const float*)d_in[18];
    const float* gru_bih  = (const float*)d_in[19];
    const float* gru_bhh  = (const float*)d_in[20];
    const float* proj_w   = (const float*)d_in[21];
    const float* proj_b   = (const float*)d_in[22];

    // ---- workspace (R13 layout, proven) ----
    char* ws = (char*)d_ws;
    float* enc_in = (float*)(ws);                                  // [6144,192] f32 (front-end)
    __hip_bfloat16* ei_hi = (__hip_bfloat16*)(ws + 4718592);       // [6144,192]
    __hip_bfloat16* ei_lo = (__hip_bfloat16*)(ws + 7077888);       // [6144,192]
    __hip_bfloat16* enc_hi = (__hip_bfloat16*)(ws);                // [6144,256] (phase2)
    __hip_bfloat16* enc_lo = (__hip_bfloat16*)(ws + 3145728);      // [6144,256] (phase2)
    char* R1 = ws + 9437184;                                       // 25.17 MB region
    float* gi2 = (float*)R1;                                       // [2,6144,512]
    float* gh  = (float*)R1;                                       // [6144,768] (decode)
    __hip_bfloat16* cmb_ext = (__hip_bfloat16*)(R1 + 18874368);    // [2][1024][256] (decode)
    float* cmb_bias = (float*)(R1 + 18874368 + 1048576);           // [1024]
    float* hdec = (float*)(ws + 34603008);                         // [6144,256] (init C out)
    __hip_bfloat16* h_hi = (__hip_bfloat16*)(ws + 40894464);       // [6144,256]
    __hip_bfloat16* h_lo = (__hip_bfloat16*)(ws + 44040192);       // [6144,256]
    float* git  = (float*)(ws + 47185920);                         // [200,768]
    float* whht = (float*)(ws + 47800320);                         // [2,128,128,4]
    __hip_bfloat16* wre_ext  = (__hip_bfloat16*)(ws + 48349184);   // [2][64][192]
    __hip_bfloat16* wfw_ext  = (__hip_bfloat16*)(ws + 48398336);   // [2][512][192]
    __hip_bfloat16* wbw_ext  = (__hip_bfloat16*)(ws + 48791552);   // [2][512][192]
    __hip_bfloat16* tag_ext  = (__hip_bfloat16*)(ws + 49184768);   // [2][640][256]
    __hip_bfloat16* init_ext = (__hip_bfloat16*)(ws + 49840128);   // [2][256][256]

    float* out_tag = (float*)d_out;                                // [6144,600]
    float* out_lem = out_tag + (size_t)NROWS * NTAGS;              // [6144,24,200]

    // ---- front-end (conv gathers ce inline; no ce64 pass) ----
    repack192_k<<<48, 256, 0, stream>>>(conv_w, wre_ext);
    wv_k<<<3072, 256, 0, stream>>>(word_ids, word_emb, enc_in);
    conv_k<<<192, 256, 0, stream>>>(char_ids, char_emb,
                                    (const ushort*)wre_ext, conv_b, enc_in);
    eisplit_k<<<4608, 256, 0, stream>>>(enc_in, ei_hi, ei_lo);
    wsplit_k<<<384, 256, 0, stream>>>(fw_wih, wfw_ext, 512, 512, 192);
    wsplit_k<<<384, 256, 0, stream>>>(bw_wih, wbw_ext, 512, 512, 192);

    // ---- LSTM input gates (MFMA), then recurrence ----
    gemm3_k<0,0,192><<<dim3(48,4), 256, 0, stream>>>((const ushort*)ei_hi, (const ushort*)ei_lo,
        (const ushort*)wfw_ext, (const ushort*)(wfw_ext + 512*192), fw_b, gi2,
        nullptr, nullptr, 512, 512);
    gemm3_k<0,0,192><<<dim3(48,4), 256, 0, stream>>>((const ushort*)ei_hi, (const ushort*)ei_lo,
        (const ushort*)wbw_ext, (const ushort*)(wbw_ext + 512*192), bw_b, gi2 + (size_t)NROWS*512,
        nullptr, nullptr, 512, 512);
    whht_k<<<512, 256, 0, stream>>>(fw_whh, bw_whh, whht);
    lstm_k<<<128, 1024, 0, stream>>>(gi2, whht, enc_hi, enc_lo);

    // ---- heads (MFMA) + decode prep ----
    cmbsplit_k<<<1024, 256, 0, stream>>>(gru_whh, proj_w, gru_bhh, proj_b, cmb_ext, cmb_bias);
    wsplit_k<<<640, 256, 0, stream>>>(tag_w, tag_ext, 600, 640, 256);
    wsplit_k<<<256, 256, 0, stream>>>(init_w, init_ext, 256, 256, 256);
    gitab_k<<<600, 256, 0, stream>>>(lemma_emb, gru_wih, gru_bih, git);
    gemm3_k<0,0,256><<<dim3(48,5), 256, 0, stream>>>((const ushort*)enc_hi, (const ushort*)enc_lo,
        (const ushort*)tag_ext, (const ushort*)(tag_ext + 640*256), tag_b, out_tag,
        nullptr, nullptr, NTAGS, NTAGS);
    gemm3_k<1,1,256><<<dim3(48,2), 256, 0, stream>>>((const ushort*)enc_hi, (const ushort*)enc_lo,
        (const ushort*)init_ext, (const ushort*)(init_ext + 256*256), init_b, hdec,
        (ushort*)h_hi, (ushort*)h_lo, 256, 256);

    // ---- greedy GRU decode: 24 x {LDS-staged combined GEMM, argmax+update} + logits-only final ----
    const ushort* cmb_hi = (const ushort*)cmb_ext;
    const ushort* cmb_lo = cmb_hi + 1024 * 256;
    for (int s = 0; s < LMAXD; ++s) {
        float* lem = (s > 0) ? (out_lem + (size_t)(s - 1) * VCD) : nullptr;
        gemmC_k<<<dim3(96,8), 256, 0, stream>>>((const ushort*)h_hi, (const ushort*)h_lo,
            cmb_hi, cmb_lo, cmb_bias, gh, lem, 768);
        argupd_k<<<NROWS, 256, 0, stream>>>(gh, git, lem, (ushort*)h_hi, (ushort*)h_lo);
    }
    // final: logits_23 = h_24 @ proj only (grid 96x2, ncol_gh=0 -> all cols to lem path)
    gemmC_k<<<dim3(96,2), 256, 0, stream>>>((const ushort*)h_hi, (const ushort*)h_lo,
        cmb_hi + 768 * 256, cmb_lo + 768 * 256, cmb_bias + 768,
        nullptr, out_lem + (size_t)(LMAXD - 1) * VCD, 0);
}